// Round 8
// baseline (80.741 us; speedup 1.0000x reference)
//
#include <hip/hip_runtime.h>
#include <math.h>

#define NQ 10
#define NL 4
#define NGATES (NL * NQ)
#define NTHREADS 256
#define BPW 2                    // batch elements per wave
#define WAVES 4                  // waves per block

typedef float f32x2 __attribute__((ext_vector_type(2)));

#if __has_builtin(__builtin_amdgcn_permlane32_swap)
#define HAVE_PLSWAP 1
#else
#define HAVE_PLSWAP 0
#endif

// ---------------------------------------------------------------------------
// Physical bit layout (10-bit state index split lane(6)/reg(4)):
//   qubit0 -> lane 16   qubit1 -> lane 8   qubit2 -> lane 4   (ds_swizzle bits)
//   qubit7 -> lane 32 (permlane)  qubit8 -> lane 2 (DPP)  qubit9 -> lane 1 (DPP)
//   qubit3 -> reg 8   qubit4 -> reg 4   qubit5 -> reg 2   qubit6 -> reg 1
// CNOT chain K = prefix-parity matrix; CNOTs absorbed into basis relabeling.
// Gate on qubit q in layer l: xor-mask m = K^{-l} e_q, select s = row_q(K^l).
// All 40 (mask, select) pairs constexpr (validated rounds 2-7).
// 2 batch elements per wave: two independent state chains give the scheduler
// independent work to hide ds_swizzle/LDS/FMA latency (only 1 wave/SIMD).
// ---------------------------------------------------------------------------

// 32-bit xor-exchange by compile-time lane mask XM
template<int XM>
__device__ __forceinline__ float exch1(float v, bool selP) {
    if constexpr (XM == 0) return v;
    int x = __float_as_int(v);
    constexpr int low = XM & 31;
    if constexpr (low == 1)      x = __builtin_amdgcn_mov_dpp(x, 0xB1, 0xF, 0xF, true);
    else if constexpr (low == 2) x = __builtin_amdgcn_mov_dpp(x, 0x4E, 0xF, 0xF, true);
    else if constexpr (low == 3) x = __builtin_amdgcn_mov_dpp(x, 0x1B, 0xF, 0xF, true);
    else if constexpr (low != 0) x = __builtin_amdgcn_ds_swizzle(x, (low << 10) | 0x1F);
    if constexpr ((XM & 32) != 0) {
#if HAVE_PLSWAP
        auto r = __builtin_amdgcn_permlane32_swap((unsigned)x, (unsigned)x, false, false);
        x = selP ? (int)r[0] : (int)r[1];
#else
        x = __float_as_int(__shfl_xor(__int_as_float(x), 32, 64));
#endif
    }
    return __int_as_float(x);
}

template<int XM>
__device__ __forceinline__ f32x2 exch2(f32x2 v, bool selP) {
    f32x2 r;
    r.x = exch1<XM>(v.x, selP);
    r.y = exch1<XM>(v.y, selP);
    return r;
}

// complex t = A*st + B*pst in 4 VOP3P packed-f32 ops (validated R5-R7)
__device__ __forceinline__ f32x2 cfma4(f32x2 A, f32x2 st, f32x2 B, f32x2 pst) {
    f32x2 t;
    asm("v_pk_mul_f32 %0, %1, %2 op_sel:[0,0] op_sel_hi:[0,1]\n\t"
        "v_pk_fma_f32 %0, %1, %2, %0 op_sel:[1,1,0] op_sel_hi:[1,0,1] neg_lo:[0,1,0]\n\t"
        "v_pk_fma_f32 %0, %3, %4, %0 op_sel:[0,0,0] op_sel_hi:[0,1,1]\n\t"
        "v_pk_fma_f32 %0, %3, %4, %0 op_sel:[1,1,0] op_sel_hi:[1,0,1] neg_lo:[0,1,0]"
        : "=&v"(t)
        : "v"(A), "v"(st), "v"(B), "v"(pst));
    return t;
}

// generalized 1q gate applied to BOTH chains; coefficient selects shared.
template<int XM, int XR, int SL, int SR>
__device__ __forceinline__ void gate2(f32x2 (&sa)[16], f32x2 (&sb)[16],
                                      const f32x2 (&g4)[4], int lane, bool selP) {
    bool hl = (SL != 0) && ((__popc(lane & SL) & 1) != 0);
    f32x2 A0, B0, A1, B1;
    A0.x = hl ? g4[3].x : g4[0].x;  A0.y = hl ? g4[3].y : g4[0].y;
    B0.x = hl ? g4[2].x : g4[1].x;  B0.y = hl ? g4[2].y : g4[1].y;
    A1.x = hl ? g4[0].x : g4[3].x;  A1.y = hl ? g4[0].y : g4[3].y;
    B1.x = hl ? g4[1].x : g4[2].x;  B1.y = hl ? g4[1].y : g4[2].y;
    f32x2 pa[16], pb[16];
    #pragma unroll
    for (int r = 0; r < 16; ++r) {
        pa[r] = exch2<XM>(sa[r ^ XR], selP);
        pb[r] = exch2<XM>(sb[r ^ XR], selP);
    }
    #pragma unroll
    for (int r = 0; r < 16; ++r) {
        const bool p1 = (__builtin_popcount(r & SR) & 1) != 0;  // compile-time
        f32x2 Ar = p1 ? A1 : A0;
        f32x2 Br = p1 ? B1 : B0;
        sa[r] = cfma4(Ar, sa[r], Br, pa[r]);
        sb[r] = cfma4(Ar, sb[r], Br, pb[r]);
    }
}

// 6-stage signed butterfly: lane L ends with sum_j (-1)^{popcount(L&j)} v_j
__device__ __forceinline__ float wht6(float v, int lane, bool selP) {
    float t;
    t = exch1<1>(v, selP);   v = (lane & 1)  ? (t - v) : (v + t);
    t = exch1<2>(v, selP);   v = (lane & 2)  ? (t - v) : (v + t);
    t = exch1<4>(v, selP);   v = (lane & 4)  ? (t - v) : (v + t);
    t = exch1<8>(v, selP);   v = (lane & 8)  ? (t - v) : (v + t);
    t = exch1<16>(v, selP);  v = (lane & 16) ? (t - v) : (v + t);
    t = exch1<32>(v, selP);  v = (lane & 32) ? (t - v) : (v + t);
    return v;
}

__device__ __forceinline__ void init_state(const float* __restrict__ x, int b,
                                           int lane, f32x2 (&st)[16]) {
    float c[NQ], s[NQ];
    #pragma unroll
    for (int q = 0; q < NQ; ++q) {
        float h = 0.5f * x[b * NQ + q];
        c[q] = __cosf(h);  s[q] = __sinf(h);
    }
    float lf = ((lane & 16) ? s[0] : c[0]) * ((lane & 8) ? s[1] : c[1]) *
               ((lane &  4) ? s[2] : c[2]) * ((lane & 32) ? s[7] : c[7]) *
               ((lane &  2) ? s[8] : c[8]) * ((lane &  1) ? s[9] : c[9]);
    #pragma unroll
    for (int r = 0; r < 16; ++r) {
        st[r].x = lf * ((r & 8) ? s[3] : c[3]) * ((r & 4) ? s[4] : c[4]) *
                       ((r & 2) ? s[5] : c[5]) * ((r & 1) ? s[6] : c[6]);
        st[r].y = 0.0f;
    }
}

__device__ __forceinline__ void epilogue(const f32x2 (&st)[16], int lane,
                                         bool selP, float* __restrict__ o) {
    float p[16];
    #pragma unroll
    for (int r = 0; r < 16; ++r) p[r] = st[r].x * st[r].x + st[r].y * st[r].y;
    float a[8], f8 = 0.0f;
    #pragma unroll
    for (int r = 0; r < 8; ++r) { a[r] = p[r] + p[r + 8]; f8 += p[r] - p[r + 8]; }
    float c4[4], f4 = 0.0f;
    #pragma unroll
    for (int r = 0; r < 4; ++r) { c4[r] = a[r] + a[r + 4]; f4 += a[r] - a[r + 4]; }
    float e2[2], f2 = 0.0f;
    #pragma unroll
    for (int r = 0; r < 2; ++r) { e2[r] = c4[r] + c4[r + 2]; f2 += c4[r] - c4[r + 2]; }
    float P  = e2[0] + e2[1];
    float f1 = e2[0] - e2[1];

    float wP = wht6(P,  lane, selP);
    float w8 = wht6(f8, lane, selP);
    float w4 = wht6(f4, lane, selP);
    float w2 = wht6(f2, lane, selP);
    float w1 = wht6(f1, lane, selP);

    // rows of K^4: {i, i-4, i-8} -> (value, lane index)
    if (lane == 16) { o[0] = wP; o[4] = w4; }
    if (lane ==  8) { o[1] = wP; o[5] = w2; }
    if (lane ==  4) { o[2] = wP; o[6] = w1; }
    if (lane ==  0) { o[3] = w8; }
    if (lane == 32) { o[7] = w8; }
    if (lane == 18) { o[8] = w4; }
    if (lane ==  9) { o[9] = w2; }
}

__global__ __launch_bounds__(NTHREADS, 1) void qlayer_kernel(
    const float* __restrict__ x,
    const float* __restrict__ qp,
    float* __restrict__ out,
    int B)
{
    __shared__ f32x2 su[NGATES][4];   // {u00, u01, u10, u11} as (re,im) pairs

    const int t = threadIdx.x;
    // --- build gate matrices U = Rz @ Ry @ Rx, threads 0..39 ---
    if (t < NGATES) {
        float w0 = qp[t * 3 + 0], w1 = qp[t * 3 + 1], w2 = qp[t * 3 + 2];
        float cx = __cosf(0.5f * w0), sx = __sinf(0.5f * w0);
        float cy = __cosf(0.5f * w1), sy = __sinf(0.5f * w1);
        float er = __cosf(0.5f * w2), ei = -__sinf(0.5f * w2);   // ez = exp(-i w2/2)
        float m00r =  cy * cx, m00i =  sy * sx;
        float m01r = -sy * cx, m01i = -cy * sx;
        float m10r =  sy * cx, m10i = -cy * sx;
        float m11r =  cy * cx, m11i = -sy * sx;
        f32x2 v;
        v.x = er * m00r - ei * m00i;  v.y = er * m00i + ei * m00r;  su[t][0] = v;
        v.x = er * m01r - ei * m01i;  v.y = er * m01i + ei * m01r;  su[t][1] = v;
        v.x = er * m10r + ei * m10i;  v.y = er * m10i - ei * m10r;  su[t][2] = v;
        v.x = er * m11r + ei * m11i;  v.y = er * m11i - ei * m11r;  su[t][3] = v;
    }
    __syncthreads();

    const int lane = t & 63;
    const int wave = t >> 6;
    const int b0 = (blockIdx.x * WAVES + wave) * BPW;
    if (b0 >= B) return;

    // runtime probe: which permlane32_swap output holds the lane^32 partner
    bool selP = false;
#if HAVE_PLSWAP
    {
        auto pr = __builtin_amdgcn_permlane32_swap((unsigned)lane, (unsigned)lane, false, false);
        selP = ((int)pr[0] == (lane ^ 32));
    }
#endif

    f32x2 sa[16], sb[16];
    init_state(x, b0, lane, sa);
    init_state(x, (b0 + 1 < B) ? b0 + 1 : b0, lane, sb);

// per-layer: prefetch all 10 gates' coefficients into registers (one LDS
// latency exposure per layer), then 10 dual-chain gates.
#define PREFETCH(L)                                                   \
    f32x2 cf[NQ][4];                                                  \
    _Pragma("unroll")                                                 \
    for (int q = 0; q < NQ; ++q) {                                    \
        cf[q][0] = su[(L)*NQ + q][0];  cf[q][1] = su[(L)*NQ + q][1];  \
        cf[q][2] = su[(L)*NQ + q][2];  cf[q][3] = su[(L)*NQ + q][3];  \
    }
#define GATE(Q, XM, XR, SLm, SRm) \
    gate2<XM, XR, SLm, SRm>(sa, sb, cf[Q], lane, selP);

    { // layer 0 (A = I)
        PREFETCH(0)
        GATE(0, 16,0, 16,0)  GATE(1, 8,0, 8,0)    GATE(2, 4,0, 4,0)
        GATE(3, 0,8, 0,8)    GATE(4, 0,4, 0,4)    GATE(5, 0,2, 0,2)
        GATE(6, 0,1, 0,1)    GATE(7, 32,0, 32,0)  GATE(8, 2,0, 2,0)
        GATE(9, 1,0, 1,0)
    }
    { // layer 1 (A = K)
        PREFETCH(1)
        GATE(0, 24,0, 16,0)  GATE(1, 12,0, 24,0)  GATE(2, 4,8, 28,0)
        GATE(3, 0,12, 28,8)  GATE(4, 0,6, 28,12)  GATE(5, 0,3, 28,14)
        GATE(6, 32,1, 28,15) GATE(7, 34,0, 60,15) GATE(8, 3,0, 62,15)
        GATE(9, 1,0, 63,15)
    }
    { // layer 2 (A = K^2)
        PREFETCH(2)
        GATE(0, 20,0, 16,0)  GATE(1, 8,8, 8,0)    GATE(2, 4,4, 20,0)
        GATE(3, 0,10, 8,8)   GATE(4, 0,5, 20,4)   GATE(5, 32,2, 8,10)
        GATE(6, 2,1, 20,5)   GATE(7, 33,0, 40,10) GATE(8, 2,0, 22,5)
        GATE(9, 1,0, 41,10)
    }
    { // layer 3 (A = K^3)
        PREFETCH(3)
        GATE(0, 28,8, 16,0)  GATE(1, 12,12, 24,0) GATE(2, 4,14, 12,0)
        GATE(3, 0,15, 4,8)   GATE(4, 32,7, 16,12) GATE(5, 34,3, 24,6)
        GATE(6, 35,1, 12,3)  GATE(7, 35,0, 36,9)  GATE(8, 3,0, 50,12)
        GATE(9, 1,0, 27,6)
    }
#undef GATE
#undef PREFETCH

    epilogue(sa, lane, selP, out + b0 * NQ);
    if (b0 + 1 < B) epilogue(sb, lane, selP, out + (b0 + 1) * NQ);
}

extern "C" void kernel_launch(void* const* d_in, const int* in_sizes, int n_in,
                              void* d_out, int out_size, void* d_ws, size_t ws_size,
                              hipStream_t stream) {
    const float* x  = (const float*)d_in[0];
    const float* qp = (const float*)d_in[1];
    float* out = (float*)d_out;
    const int B = in_sizes[0] / NQ;
    const int bpb = WAVES * BPW;                     // batches per block
    const int blocks = (B + bpb - 1) / bpb;
    qlayer_kernel<<<blocks, NTHREADS, 0, stream>>>(x, qp, out, B);
}

// Round 9
// 77.227 us; speedup vs baseline: 1.0455x; 1.0455x over previous
//
#include <hip/hip_runtime.h>
#include <math.h>

#define NQ 10
#define NL 4
#define NGATES (NL * NQ)
#define NTHREADS 256
#define WPB 4   // waves per block

typedef float f32x2 __attribute__((ext_vector_type(2)));

#if __has_builtin(__builtin_amdgcn_permlane32_swap)
#define HAVE_PL32 1
#else
#define HAVE_PL32 0
#endif
#if __has_builtin(__builtin_amdgcn_permlane16_swap)
#define HAVE_PL16 1
#else
#define HAVE_PL16 0
#endif

// ---------------------------------------------------------------------------
// Physical bit layout (10-bit state index split lane(6)/reg(4)):
//   qubit0 -> lane 4  (ds_swizzle — ONLY swizzle bit; q0 appears only in its
//                      own gates' xor-masks, so just 4 swizzle-gates total)
//   qubit1 -> lane 32 (permlane32_swap, VALU)
//   qubit2 -> lane 16 (permlane16_swap, VALU)
//   qubit7 -> lane 8  (DPP row_ror:8, VALU)
//   qubit8 -> lane 2  (DPP quad_perm, VALU)
//   qubit9 -> lane 1  (DPP quad_perm, VALU)
//   qubit3 -> reg 8   qubit4 -> reg 4   qubit5 -> reg 2   qubit6 -> reg 1
// CNOT chain K = prefix-parity; CNOTs absorbed into basis relabeling.
// Gate (l,q): xor-mask m = K^{-l} e_q, select s = row_q(K^l)  (qubit-space
// sets validated rounds 2-8; remapped to the new bit assignment here).
// ---------------------------------------------------------------------------

// 32-bit xor-exchange by compile-time lane mask XM
template<int XM>
__device__ __forceinline__ float exch1(float v, bool sp32, bool sp16) {
    if constexpr (XM == 0) return v;
    int x = __float_as_int(v);
    constexpr int low = XM & 31;
    if constexpr (low == 1)       x = __builtin_amdgcn_mov_dpp(x, 0xB1, 0xF, 0xF, true);
    else if constexpr (low == 2)  x = __builtin_amdgcn_mov_dpp(x, 0x4E, 0xF, 0xF, true);
    else if constexpr (low == 3)  x = __builtin_amdgcn_mov_dpp(x, 0x1B, 0xF, 0xF, true);
    else if constexpr (low == 7)  x = __builtin_amdgcn_mov_dpp(x, 0x141, 0xF, 0xF, true);
    else if constexpr (low == 8)  x = __builtin_amdgcn_mov_dpp(x, 0x128, 0xF, 0xF, true);
    else if constexpr (low == 9)  { x = __builtin_amdgcn_mov_dpp(x, 0x128, 0xF, 0xF, true);
                                    x = __builtin_amdgcn_mov_dpp(x, 0xB1, 0xF, 0xF, true); }
    else if constexpr (low == 10) { x = __builtin_amdgcn_mov_dpp(x, 0x128, 0xF, 0xF, true);
                                    x = __builtin_amdgcn_mov_dpp(x, 0x4E, 0xF, 0xF, true); }
    else if constexpr (low == 11) { x = __builtin_amdgcn_mov_dpp(x, 0x128, 0xF, 0xF, true);
                                    x = __builtin_amdgcn_mov_dpp(x, 0x1B, 0xF, 0xF, true); }
    else if constexpr (low == 15) x = __builtin_amdgcn_mov_dpp(x, 0x140, 0xF, 0xF, true);
    else if constexpr (low == 16) {
#if HAVE_PL16
        auto r = __builtin_amdgcn_permlane16_swap((unsigned)x, (unsigned)x, false, false);
        x = sp16 ? (int)r[0] : (int)r[1];
#else
        x = __builtin_amdgcn_ds_swizzle(x, (16 << 10) | 0x1F);
#endif
    }
    else if constexpr (low != 0)  x = __builtin_amdgcn_ds_swizzle(x, (low << 10) | 0x1F);
    if constexpr ((XM & 32) != 0) {
#if HAVE_PL32
        auto r = __builtin_amdgcn_permlane32_swap((unsigned)x, (unsigned)x, false, false);
        x = sp32 ? (int)r[0] : (int)r[1];
#else
        x = __float_as_int(__shfl_xor(__int_as_float(x), 32, 64));
#endif
    }
    return __int_as_float(x);
}

template<int XM>
__device__ __forceinline__ f32x2 exch2(f32x2 v, bool sp32, bool sp16) {
    f32x2 r;
    r.x = exch1<XM>(v.x, sp32, sp16);
    r.y = exch1<XM>(v.y, sp32, sp16);
    return r;
}

// complex t = A*st + B*pst in 4 VOP3P packed-f32 ops (validated R5-R8)
__device__ __forceinline__ f32x2 cfma4(f32x2 A, f32x2 st, f32x2 B, f32x2 pst) {
    f32x2 t;
    asm("v_pk_mul_f32 %0, %1, %2 op_sel:[0,0] op_sel_hi:[0,1]\n\t"
        "v_pk_fma_f32 %0, %1, %2, %0 op_sel:[1,1,0] op_sel_hi:[1,0,1] neg_lo:[0,1,0]\n\t"
        "v_pk_fma_f32 %0, %3, %4, %0 op_sel:[0,0,0] op_sel_hi:[0,1,1]\n\t"
        "v_pk_fma_f32 %0, %3, %4, %0 op_sel:[1,1,0] op_sel_hi:[1,0,1] neg_lo:[0,1,0]"
        : "=&v"(t)
        : "v"(A), "v"(st), "v"(B), "v"(pst));
    return t;
}

// generalized 1q gate: pair (p, p^m); select h = parity(p & s)
template<int XM, int XR, int SL, int SR>
__device__ __forceinline__ void gate(f32x2 (&st)[16], const f32x2 (&g4)[4],
                                     int lane, bool sp32, bool sp16) {
    bool hl = (SL != 0) && ((__popc(lane & SL) & 1) != 0);
    f32x2 A0, B0, A1, B1;
    A0.x = hl ? g4[3].x : g4[0].x;  A0.y = hl ? g4[3].y : g4[0].y;
    B0.x = hl ? g4[2].x : g4[1].x;  B0.y = hl ? g4[2].y : g4[1].y;
    A1.x = hl ? g4[0].x : g4[3].x;  A1.y = hl ? g4[0].y : g4[3].y;
    B1.x = hl ? g4[1].x : g4[2].x;  B1.y = hl ? g4[1].y : g4[2].y;
    f32x2 pst[16];
    #pragma unroll
    for (int r = 0; r < 16; ++r) pst[r] = exch2<XM>(st[r ^ XR], sp32, sp16);
    #pragma unroll
    for (int r = 0; r < 16; ++r) {
        const bool p1 = (__builtin_popcount(r & SR) & 1) != 0;  // compile-time
        f32x2 Ar = p1 ? A1 : A0;
        f32x2 Br = p1 ? B1 : B0;
        st[r] = cfma4(Ar, st[r], Br, pst[r]);
    }
}

// 6-stage signed butterfly: lane L ends with sum_j (-1)^{popcount(L&j)} v_j
__device__ __forceinline__ float wht6(float v, int lane, bool sp32, bool sp16) {
    float t;
    t = exch1<1>(v, sp32, sp16);   v = (lane & 1)  ? (t - v) : (v + t);
    t = exch1<2>(v, sp32, sp16);   v = (lane & 2)  ? (t - v) : (v + t);
    t = exch1<4>(v, sp32, sp16);   v = (lane & 4)  ? (t - v) : (v + t);
    t = exch1<8>(v, sp32, sp16);   v = (lane & 8)  ? (t - v) : (v + t);
    t = exch1<16>(v, sp32, sp16);  v = (lane & 16) ? (t - v) : (v + t);
    t = exch1<32>(v, sp32, sp16);  v = (lane & 32) ? (t - v) : (v + t);
    return v;
}

__global__ __launch_bounds__(NTHREADS, 2) void qlayer_kernel(
    const float* __restrict__ x,
    const float* __restrict__ qp,
    float* __restrict__ out,
    int B)
{
    __shared__ f32x2 su[NGATES][4];   // {u00, u01, u10, u11} as (re,im) pairs

    const int t = threadIdx.x;
    // --- build gate matrices U = Rz @ Ry @ Rx, threads 0..39 ---
    if (t < NGATES) {
        float w0 = qp[t * 3 + 0], w1 = qp[t * 3 + 1], w2 = qp[t * 3 + 2];
        float cx = __cosf(0.5f * w0), sx = __sinf(0.5f * w0);
        float cy = __cosf(0.5f * w1), sy = __sinf(0.5f * w1);
        float er = __cosf(0.5f * w2), ei = -__sinf(0.5f * w2);   // ez = exp(-i w2/2)
        float m00r =  cy * cx, m00i =  sy * sx;
        float m01r = -sy * cx, m01i = -cy * sx;
        float m10r =  sy * cx, m10i = -cy * sx;
        float m11r =  cy * cx, m11i = -sy * sx;
        f32x2 v;
        v.x = er * m00r - ei * m00i;  v.y = er * m00i + ei * m00r;  su[t][0] = v;
        v.x = er * m01r - ei * m01i;  v.y = er * m01i + ei * m01r;  su[t][1] = v;
        v.x = er * m10r + ei * m10i;  v.y = er * m10i - ei * m10r;  su[t][2] = v;
        v.x = er * m11r + ei * m11i;  v.y = er * m11i - ei * m11r;  su[t][3] = v;
    }
    __syncthreads();

    const int lane = t & 63;
    const int b = blockIdx.x * WPB + (t >> 6);
    if (b >= B) return;

    // runtime probes: which swap output holds the xor partner
    bool sp32 = false, sp16 = false;
#if HAVE_PL32
    {
        auto pr = __builtin_amdgcn_permlane32_swap((unsigned)lane, (unsigned)lane, false, false);
        sp32 = ((int)pr[0] == (lane ^ 32));
    }
#endif
#if HAVE_PL16
    {
        auto pr = __builtin_amdgcn_permlane16_swap((unsigned)lane, (unsigned)lane, false, false);
        sp16 = ((int)pr[0] == (lane ^ 16));
    }
#endif

    float c[NQ], s[NQ];
    #pragma unroll
    for (int q = 0; q < NQ; ++q) {
        float h = 0.5f * x[b * NQ + q];
        c[q] = __cosf(h);  s[q] = __sinf(h);
    }

    // initial product state per physical layout:
    // lane bits: 4->q0, 32->q1, 16->q2, 8->q7, 2->q8, 1->q9
    float lf = ((lane &  4) ? s[0] : c[0]) * ((lane & 32) ? s[1] : c[1]) *
               ((lane & 16) ? s[2] : c[2]) * ((lane &  8) ? s[7] : c[7]) *
               ((lane &  2) ? s[8] : c[8]) * ((lane &  1) ? s[9] : c[9]);
    f32x2 st[16];
    #pragma unroll
    for (int r = 0; r < 16; ++r) {
        st[r].x = lf * ((r & 8) ? s[3] : c[3]) * ((r & 4) ? s[4] : c[4]) *
                       ((r & 2) ? s[5] : c[5]) * ((r & 1) ? s[6] : c[6]);
        st[r].y = 0.0f;
    }

// per-layer: prefetch all 10 gates' coefficients into registers (one LDS
// latency exposure per layer), then 10 gates.
#define PREFETCH(L)                                                   \
    f32x2 cf[NQ][4];                                                  \
    _Pragma("unroll")                                                 \
    for (int q = 0; q < NQ; ++q) {                                    \
        cf[q][0] = su[(L)*NQ + q][0];  cf[q][1] = su[(L)*NQ + q][1];  \
        cf[q][2] = su[(L)*NQ + q][2];  cf[q][3] = su[(L)*NQ + q][3];  \
    }
#define GATE(Q, XM, XR, SLm, SRm) \
    gate<XM, XR, SLm, SRm>(st, cf[Q], lane, sp32, sp16);

    { // layer 0 (A = I): m={q}, s={q}
        PREFETCH(0)
        GATE(0, 4,0, 4,0)     GATE(1, 32,0, 32,0)  GATE(2, 16,0, 16,0)
        GATE(3, 0,8, 0,8)     GATE(4, 0,4, 0,4)    GATE(5, 0,2, 0,2)
        GATE(6, 0,1, 0,1)     GATE(7, 8,0, 8,0)    GATE(8, 2,0, 2,0)
        GATE(9, 1,0, 1,0)
    }
    { // layer 1 (A = K): m={q,q+1}, s={0..q}
        PREFETCH(1)
        GATE(0, 36,0, 4,0)    GATE(1, 48,0, 36,0)  GATE(2, 16,8, 52,0)
        GATE(3, 0,12, 52,8)   GATE(4, 0,6, 52,12)  GATE(5, 0,3, 52,14)
        GATE(6, 8,1, 52,15)   GATE(7, 10,0, 60,15) GATE(8, 3,0, 62,15)
        GATE(9, 1,0, 63,15)
    }
    { // layer 2 (A = K^2): m={q,q+2}, s={q,q-2,...}
        PREFETCH(2)
        GATE(0, 20,0, 4,0)    GATE(1, 32,8, 32,0)  GATE(2, 16,4, 20,0)
        GATE(3, 0,10, 32,8)   GATE(4, 0,5, 20,4)   GATE(5, 8,2, 32,10)
        GATE(6, 2,1, 20,5)    GATE(7, 9,0, 40,10)  GATE(8, 2,0, 22,5)
        GATE(9, 1,0, 41,10)
    }
    { // layer 3 (A = K^3): m={q..q+3}, s={q,q-1,q-4,q-5,q-8,q-9}
        PREFETCH(3)
        GATE(0, 52,8, 4,0)    GATE(1, 48,12, 36,0) GATE(2, 16,14, 48,0)
        GATE(3, 0,15, 16,8)   GATE(4, 8,7, 4,12)   GATE(5, 10,3, 36,6)
        GATE(6, 11,1, 48,3)   GATE(7, 11,0, 24,9)  GATE(8, 3,0, 14,12)
        GATE(9, 1,0, 39,6)
    }
#undef GATE
#undef PREFETCH

    // epilogue: probabilities, reg-space signed folds, 5 lane-space WHTs
    float p[16];
    #pragma unroll
    for (int r = 0; r < 16; ++r) p[r] = st[r].x * st[r].x + st[r].y * st[r].y;
    float a[8], f8 = 0.0f;
    #pragma unroll
    for (int r = 0; r < 8; ++r) { a[r] = p[r] + p[r + 8]; f8 += p[r] - p[r + 8]; }
    float c4[4], f4 = 0.0f;
    #pragma unroll
    for (int r = 0; r < 4; ++r) { c4[r] = a[r] + a[r + 4]; f4 += a[r] - a[r + 4]; }
    float e2[2], f2 = 0.0f;
    #pragma unroll
    for (int r = 0; r < 2; ++r) { e2[r] = c4[r] + c4[r + 2]; f2 += c4[r] - c4[r + 2]; }
    float P  = e2[0] + e2[1];
    float f1 = e2[0] - e2[1];

    float wP = wht6(P,  lane, sp32, sp16);
    float w8 = wht6(f8, lane, sp32, sp16);
    float w4 = wht6(f4, lane, sp32, sp16);
    float w2 = wht6(f2, lane, sp32, sp16);
    float w1 = wht6(f1, lane, sp32, sp16);

    // rows of K^4: {i, i-4, i-8} mapped to (fold, lane index) in NEW layout:
    // q0:{0}->wP@4  q1:{1}->wP@32  q2:{2}->wP@16  q3:{3}->w8@0
    // q4:{4,0}->w4@4  q5:{5,1}->w2@32  q6:{6,2}->w1@16
    // q7:{7,3}->w8@8  q8:{8,4,0}->w4@6  q9:{9,5,1}->w2@33
    float* o = out + b * NQ;
    if (lane ==  4) { o[0] = wP; o[4] = w4; }
    if (lane == 32) { o[1] = wP; o[5] = w2; }
    if (lane == 16) { o[2] = wP; o[6] = w1; }
    if (lane ==  0) { o[3] = w8; }
    if (lane ==  8) { o[7] = w8; }
    if (lane ==  6) { o[8] = w4; }
    if (lane == 33) { o[9] = w2; }
}

extern "C" void kernel_launch(void* const* d_in, const int* in_sizes, int n_in,
                              void* d_out, int out_size, void* d_ws, size_t ws_size,
                              hipStream_t stream) {
    const float* x  = (const float*)d_in[0];
    const float* qp = (const float*)d_in[1];
    float* out = (float*)d_out;
    const int B = in_sizes[0] / NQ;
    const int blocks = (B + WPB - 1) / WPB;
    qlayer_kernel<<<blocks, NTHREADS, 0, stream>>>(x, qp, out, B);
}